// Round 5
// baseline (3274.662 us; speedup 1.0000x reference)
//
#include <hip/hip_runtime.h>
#include <cmath>

#define VOCAB 20000
#define EMB 300
#define FEAT 2052
#define HID 1024
#define OUTN 3000
#define NK 8
#define NS 10
#define KOBJ 36
#define BATCH 256
#define QLEN_ 14

typedef __attribute__((ext_vector_type(8))) short bf8v;
typedef __attribute__((ext_vector_type(4))) float f4v;

__device__ __forceinline__ short f2bf(float f) {
    union { float f; unsigned u; } v; v.f = f;
    unsigned r = v.u + 0x7fff + ((v.u >> 16) & 1);   // RTNE
    return (short)(r >> 16);
}
__device__ __forceinline__ float bf2f(short h) {
    union { unsigned u; float f; } v; v.u = ((unsigned)(unsigned short)h) << 16;
    return v.f;
}
__device__ __forceinline__ void gload16(const short* g, short* l) {
    typedef __attribute__((address_space(1))) void gv;
    typedef __attribute__((address_space(3))) void lv;
    __builtin_amdgcn_global_load_lds((gv*)g, (lv*)l, 16, 0, 0);
}

// ==================== universal MFMA GEMM ====================
// C = A(M,K) @ B^T. A bf16 hi[,lo], K%32==0, rows padded to tile.
// B: bf16 hi[,lo] padded  OR  (BF32) raw fp32 (N,Kf32=ldb) converted during staging.
// Epilogues: beta / bias / relu / wmul->Cf2 / mul / Cf / Cb(zero-pad) / ATTRED(raw).
struct GJob {
    const short *Ah, *Al, *Bh, *Bl;
    const float *Bf;
    long lda, ldb;
    float *Cf; short *Cb; long ldc, ldcb;
    const float *bias, *mul, *wmul; long ldmul;
    float *Cf2;
    const float *qpw; float *raw; int L;   // ATTRED
    int Nvalid, K, beta, relu;
};
struct GJobs { GJob j[2]; };

template<int PREC, int MI, int BF32>
__global__ __launch_bounds__(256)
void mgemm_k(GJobs P)
{
    const GJob jb = P.j[blockIdx.z];
    constexpr int BM  = MI * 32;
    constexpr int ASZ = BM * 32;
    constexpr int BSZ = 128 * 32;
    __shared__ short SA[ASZ];
    __shared__ short SB[BSZ];
    __shared__ short SAl[PREC == 3 ? ASZ : 16];
    __shared__ short SBl[PREC == 3 ? BSZ : 16];
    __shared__ float rawp[128];

    // block mapping
    int gx = gridDim.x, gy = gridDim.y;
    int flat = blockIdx.y * gx + blockIdx.x;
    int bx, by;
    if (gy <= 8 && (gx & 7) == 0) {      // skinny: same-bx blocks -> same XCD
        int g = flat & 7, s = flat >> 3;
        by = s % gy; bx = g + 8 * (s / gy);
    } else { bx = blockIdx.x; by = blockIdx.y; }

    int tid = threadIdx.x;
    int lane = tid & 63, wid = tid >> 6;
    int m0 = by * BM, n0 = bx * 128;
    const short* Ab  = jb.Ah + (size_t)m0 * jb.lda;
    const short* Bb  = jb.Bh + (size_t)n0 * jb.ldb;
    const short* Abl = (PREC == 3) ? jb.Al + (size_t)m0 * jb.lda : nullptr;
    const short* Bbl = (PREC == 3) ? jb.Bl + (size_t)n0 * jb.ldb : nullptr;

    constexpr int AISS = BM / 16;
    constexpr int NISS = (PREC == 3) ? 2 * (AISS + 8) : (AISS + 8);
    int rr = lane & 15;
    int cc = (lane >> 4) * 8;
    int K = jb.K;

    f4v acc[MI][4] = {};
    for (int k0 = 0; k0 < K; k0 += 32) {
        if (BF32) {
            #pragma unroll
            for (int u = wid; u < AISS; u += 4)
                gload16(Ab + (size_t)(u * 16 + rr) * jb.lda + k0 + cc, SA + u * 512);
            // B: fp32 -> bf16, written in MFMA fragment layout:
            //   shorts offset = (row>>4)*512 + (cgrp*16 + (row&15))*8
            #pragma unroll
            for (int p = 0; p < 2; p++) {
                int idx = p * 256 + tid;      // [0,512)
                int row = idx >> 2;           // [0,128)
                int cg  = idx & 3;            // [0,4)
                int n   = n0 + row;
                bool rv = n < jb.Nvalid;
                const float* src = jb.Bf + (size_t)n * jb.ldb + k0 + cg * 8;
                bf8v hv;
                #pragma unroll
                for (int e = 0; e < 8; e++) {
                    int c = k0 + cg * 8 + e;
                    float v = (rv && c < (int)jb.ldb) ? src[e] : 0.f;
                    hv[e] = f2bf(v);
                }
                *((bf8v*)(SB + (row >> 4) * 512 + (cg * 16 + (row & 15)) * 8)) = hv;
            }
        } else {
            #pragma unroll
            for (int t = wid; t < NISS; t += 4) {
                int u = t;
                const short* g; short* l;
                if (u < AISS)             {                  g = Ab  + (size_t)(u*16+rr)*jb.lda + k0 + cc; l = SA  + u*512; }
                else if (u < AISS + 8)    { u -= AISS;       g = Bb  + (size_t)(u*16+rr)*jb.ldb + k0 + cc; l = SB  + u*512; }
                else if (u < 2*AISS + 8)  { u -= AISS + 8;   g = Abl + (size_t)(u*16+rr)*jb.lda + k0 + cc; l = SAl + u*512; }
                else                      { u -= 2*AISS + 8; g = Bbl + (size_t)(u*16+rr)*jb.ldb + k0 + cc; l = SBl + u*512; }
                gload16(g, l);
            }
        }
        __syncthreads();
        {
            int wy = wid >> 1, wx = wid & 1;
            int quad = lane >> 4, l15 = lane & 15;
            const bf8v* A8 = (const bf8v*)SA;
            const bf8v* B8 = (const bf8v*)SB;
            bf8v ah[MI], bh[4];
            #pragma unroll
            for (int i = 0; i < MI; i++) ah[i] = A8[(wy*MI + i)*64 + quad*16 + l15];
            #pragma unroll
            for (int j = 0; j < 4; j++)  bh[j] = B8[(wx*4 + j)*64 + quad*16 + l15];
            if (PREC == 3) {
                const bf8v* A8l = (const bf8v*)SAl;
                const bf8v* B8l = (const bf8v*)SBl;
                bf8v al[MI], bl[4];
                #pragma unroll
                for (int i = 0; i < MI; i++) al[i] = A8l[(wy*MI + i)*64 + quad*16 + l15];
                #pragma unroll
                for (int j = 0; j < 4; j++)  bl[j] = B8l[(wx*4 + j)*64 + quad*16 + l15];
                #pragma unroll
                for (int i = 0; i < MI; i++)
                    #pragma unroll
                    for (int j = 0; j < 4; j++) {
                        acc[i][j] = __builtin_amdgcn_mfma_f32_16x16x32_bf16(ah[i], bh[j], acc[i][j], 0, 0, 0);
                        acc[i][j] = __builtin_amdgcn_mfma_f32_16x16x32_bf16(al[i], bh[j], acc[i][j], 0, 0, 0);
                        acc[i][j] = __builtin_amdgcn_mfma_f32_16x16x32_bf16(ah[i], bl[j], acc[i][j], 0, 0, 0);
                    }
            } else {
                #pragma unroll
                for (int i = 0; i < MI; i++)
                    #pragma unroll
                    for (int j = 0; j < 4; j++)
                        acc[i][j] = __builtin_amdgcn_mfma_f32_16x16x32_bf16(ah[i], bh[j], acc[i][j], 0, 0, 0);
            }
        }
        __syncthreads();
    }

    int wy = wid >> 1, wx = wid & 1;
    int quad = lane >> 4, l15 = lane & 15;
    if (jb.raw) {
        // ATTRED: raw[m] += sum_n relu(acc+bias)*qpw[b*1024+n]
        if (tid < 128) rawp[tid] = 0.f;
        __syncthreads();
        #pragma unroll
        for (int i = 0; i < MI; i++) {
            int rl = wy * (MI * 16) + i * 16 + quad * 4;
            #pragma unroll
            for (int r = 0; r < 4; r++) {
                int m = m0 + rl + r;
                int b = m / jb.L;
                float s = 0.f;
                #pragma unroll
                for (int j = 0; j < 4; j++) {
                    int n = n0 + wx * 64 + j * 16 + l15;
                    if (n < jb.Nvalid) {
                        float v = fmaxf(acc[i][j][r] + jb.bias[n], 0.f);
                        s += v * jb.qpw[(size_t)b * 1024 + n];
                    }
                }
                atomicAdd(&rawp[rl + r], s);
            }
        }
        __syncthreads();
        if (tid < BM) atomicAdd(jb.raw + m0 + tid, rawp[tid]);
    } else {
        #pragma unroll
        for (int i = 0; i < MI; i++) {
            int mb = m0 + wy * (MI * 16) + i * 16 + quad * 4;
            #pragma unroll
            for (int j = 0; j < 4; j++) {
                int n = n0 + wx * 64 + j * 16 + l15;
                bool nin = n < jb.Nvalid;
                #pragma unroll
                for (int r = 0; r < 4; r++) {
                    int m = mb + r;
                    float v = acc[i][j][r];
                    if (nin) {
                        if (jb.beta) v += jb.Cf[(size_t)m * jb.ldc + n];
                        if (jb.bias) v += jb.bias[n];
                        if (jb.relu) v = fmaxf(v, 0.f);
                        if (jb.wmul) jb.Cf2[(size_t)m * 1024 + n] = v * jb.wmul[n];
                        if (jb.mul)  v *= jb.mul[(size_t)m * jb.ldmul + n];
                        if (jb.Cf) jb.Cf[(size_t)m * jb.ldc + n] = v;
                        if (jb.Cb) jb.Cb[(size_t)m * jb.ldcb + n] = f2bf(v);
                    } else if (jb.Cb && n < jb.ldcb) {
                        jb.Cb[(size_t)m * jb.ldcb + n] = 0;
                    }
                }
            }
        }
    }
}

// ==================== fused GRU step ====================
// gh = h_old @ whhp^T in gate-interleaved layout, then pointwise, one kernel.
// whhp row' = strip*384 + gate*128 + j  maps orig row gate*1024 + strip*128 + j.
__global__ __launch_bounds__(256)
void gru_step_k(const short* __restrict__ hh, const short* __restrict__ hl,
                const float* __restrict__ hf,
                float* __restrict__ nhf, short* __restrict__ nhh, short* __restrict__ nhl,
                const short* __restrict__ wh, const short* __restrict__ wl,
                const float* __restrict__ bhh, const float* __restrict__ gi,
                const int* __restrict__ qlen, int t)
{
    __shared__ short SM[26624];   // A hi[0,1024) lo[1024,2048) Bhi[2048,14336) Blo[14336,26624)
    int tid = threadIdx.x;
    int lane = tid & 63, wid = tid >> 6;
    int bx = blockIdx.x, by = blockIdx.y;
    int rr = lane & 15, cc = (lane >> 4) * 8;
    const short* Abh = hh + (size_t)(by * 32) * 1024;
    const short* Abl = hl + (size_t)(by * 32) * 1024;
    const short* Bbh = wh + (size_t)(bx * 384) * 1024;
    const short* Bbl = wl + (size_t)(bx * 384) * 1024;

    f4v acc[2][6] = {};
    for (int k0 = 0; k0 < 1024; k0 += 32) {
        #pragma unroll
        for (int u0 = wid; u0 < 52; u0 += 4) {
            int u = u0;
            const short* g; short* l;
            if (u < 2)        {          g = Abh + (size_t)(u*16+rr)*1024 + k0 + cc; l = SM + u*512; }
            else if (u < 4)   { u -= 2;  g = Abl + (size_t)(u*16+rr)*1024 + k0 + cc; l = SM + 1024 + u*512; }
            else if (u < 28)  { u -= 4;  g = Bbh + (size_t)(u*16+rr)*1024 + k0 + cc; l = SM + 2048 + u*512; }
            else              { u -= 28; g = Bbl + (size_t)(u*16+rr)*1024 + k0 + cc; l = SM + 14336 + u*512; }
            gload16(g, l);
        }
        __syncthreads();
        {
            int quad = lane >> 4, l15 = lane & 15;
            const bf8v* A8h = (const bf8v*)SM;
            const bf8v* A8l = (const bf8v*)(SM + 1024);
            const bf8v* B8h = (const bf8v*)(SM + 2048);
            const bf8v* B8l = (const bf8v*)(SM + 14336);
            bf8v ah[2], al[2];
            #pragma unroll
            for (int i = 0; i < 2; i++) {
                ah[i] = A8h[i*64 + quad*16 + l15];
                al[i] = A8l[i*64 + quad*16 + l15];
            }
            #pragma unroll
            for (int jj = 0; jj < 6; jj++) {
                int jt = wid * 6 + jj;
                bf8v bh = B8h[jt*64 + quad*16 + l15];
                bf8v bl = B8l[jt*64 + quad*16 + l15];
                #pragma unroll
                for (int i = 0; i < 2; i++) {
                    acc[i][jj] = __builtin_amdgcn_mfma_f32_16x16x32_bf16(ah[i], bh, acc[i][jj], 0, 0, 0);
                    acc[i][jj] = __builtin_amdgcn_mfma_f32_16x16x32_bf16(al[i], bh, acc[i][jj], 0, 0, 0);
                    acc[i][jj] = __builtin_amdgcn_mfma_f32_16x16x32_bf16(ah[i], bl, acc[i][jj], 0, 0, 0);
                }
            }
        }
        __syncthreads();
    }
    // acc -> LDS (fp32 32x384), then pointwise
    float* ghs = (float*)SM;
    {
        int quad = lane >> 4, l15 = lane & 15;
        #pragma unroll
        for (int i = 0; i < 2; i++)
            #pragma unroll
            for (int jj = 0; jj < 6; jj++) {
                int col = (wid * 6 + jj) * 16 + l15;
                #pragma unroll
                for (int r = 0; r < 4; r++)
                    ghs[(i * 16 + quad * 4 + r) * 384 + col] = acc[i][jj][r];
            }
    }
    __syncthreads();
    #pragma unroll
    for (int e0 = 0; e0 < 16; e0++) {
        int e = e0 * 256 + tid;
        int bl_ = e >> 7, jj = e & 127;
        int j = bx * 128 + jj;
        int b = by * 32 + bl_;
        float hr = ghs[bl_ * 384 + jj]        + bhh[j];
        float hz = ghs[bl_ * 384 + 128 + jj]  + bhh[1024 + j];
        float hn = ghs[bl_ * 384 + 256 + jj]  + bhh[2048 + j];
        const float* gp = gi + ((size_t)b * QLEN_ + t) * 3072;
        float r = 1.f / (1.f + expf(-(gp[j] + hr)));
        float z = 1.f / (1.f + expf(-(gp[1024 + j] + hz)));
        float n = tanhf(gp[2048 + j] + r * hn);
        float ho = hf[(size_t)b * 1024 + j];
        float val = (t < qlen[b]) ? (1.f - z) * n + z * ho : ho;
        nhf[(size_t)b * 1024 + j] = val;
        short h = f2bf(val);
        nhh[(size_t)b * 1024 + j] = h;
        nhl[(size_t)b * 1024 + j] = f2bf(val - bf2f(h));
    }
}

// ==================== mega conversion kernel ====================
struct CJob {
    int type, srows, scols, dcols, nblocks, b0, txc;
    long sld, dld, nelem;
    const float* src; const int* isrc;
    short* dh; short* dl; float* df;
};
struct CJobs { CJob j[14]; int nj; };

__global__ __launch_bounds__(256)
void megacvt_k(CJobs P)
{
    __shared__ float tb[32][33];
    int bb = blockIdx.x;
    int ji = 0;
    #pragma unroll 1
    for (int q = 0; q < P.nj; q++)
        if (bb >= P.j[q].b0 && bb < P.j[q].b0 + P.j[q].nblocks) { ji = q; }
    const CJob jb = P.j[ji];
    int lb = bb - jb.b0;
    int tid = threadIdx.x;
    if (jb.type <= 1) {          // cvt (1 = gate-perm rows)
        long i = (long)lb * 256 + tid;
        if (i >= jb.nelem) return;
        int r = (int)(i / jb.dcols), c = (int)(i - (long)r * jb.dcols);
        int sr = r;
        if (jb.type == 1) sr = ((r % 384) / 128) * 1024 + (r / 384) * 128 + (r % 128);
        float v = (sr < jb.srows && c < jb.scols) ? jb.src[(size_t)sr * jb.sld + c] : 0.f;
        short h = f2bf(v);
        jb.dh[(size_t)r * jb.dld + c] = h;
        if (jb.dl) jb.dl[(size_t)r * jb.dld + c] = f2bf(v - bf2f(h));
    } else if (jb.type == 2) {   // embed
        long i = (long)lb * 256 + tid;
        if (i >= jb.nelem) return;
        int c = (int)(i % 320); int bt = (int)(i / 320);
        float v = (c < EMB) ? jb.src[(size_t)jb.isrc[bt] * EMB + c] : 0.f;
        short h = f2bf(v);
        jb.dh[i] = h;
        jb.dl[i] = f2bf(v - bf2f(h));
    } else if (jb.type == 3) {   // zero fp32
        long i = (long)lb * 256 + tid;
        if (i < jb.nelem) jb.df[i] = 0.f;
    } else {                     // packT: per slice transpose (srows x scols) -> (scols x dld)
        int tx = jb.txc;
        int tilesper = tx * ((jb.dcols + 31) / 32);   // dcols = padded srows (== dld)
        int slice = lb / tilesper, rem = lb - slice * tilesper;
        int ty_i = rem / tx, tx_i = rem - ty_i * tx;
        const float* s = jb.src + (size_t)slice * jb.srows * jb.scols;
        short* d = jb.dh + (size_t)slice * jb.scols * jb.dld;
        int f0 = ty_i * 32, o0 = tx_i * 32;
        int ttx = tid & 31, tty = tid >> 5;
        for (int i = tty; i < 32; i += 8) {
            int f = f0 + i, o = o0 + ttx;
            tb[i][ttx] = (f < jb.srows && o < jb.scols) ? s[(size_t)f * jb.scols + o] : 0.f;
        }
        __syncthreads();
        for (int i = tty; i < 32; i += 8) {
            int o = o0 + i, f = f0 + ttx;
            if (o < jb.scols && f < jb.dld) d[(size_t)o * jb.dld + f] = f2bf(tb[ttx][i]);
        }
    }
}

// ==================== small fused kernels ====================
__global__ void softmax_topk_k(float* __restrict__ att, int L, int* __restrict__ idx)
{
    int b = threadIdx.x;
    float* r = att + (size_t)b * L;
    float mx = -1e30f;
    for (int l = 0; l < L; l++) mx = fmaxf(mx, r[l]);
    float sum = 0.f;
    for (int l = 0; l < L; l++) { float e = expf(r[l] - mx); r[l] = e; sum += e; }
    float inv = 1.f / sum;
    for (int l = 0; l < L; l++) r[l] *= inv;
    if (idx) {
        bool taken[KOBJ];
        for (int l = 0; l < L; l++) taken[l] = false;
        for (int s = 0; s < NS; s++) {
            float best = -1e30f; int bi = 0;
            for (int l = 0; l < L; l++)
                if (!taken[l] && r[l] > best) { best = r[l]; bi = l; }
            taken[bi] = true;
            idx[b * NS + s] = bi;
        }
    }
}

// gather->gnodes/timg_f | kw | wsum(imatt)
__global__ void phasecprep_k(const float* __restrict__ image, const int* __restrict__ tidx,
                             const float* __restrict__ att,
                             short* __restrict__ gnodes, float* __restrict__ timg_f,
                             const float* __restrict__ mu1, const float* __restrict__ sig1,
                             const float* __restrict__ mu2, const float* __restrict__ sig2,
                             float* __restrict__ kw1, float* __restrict__ kw2,
                             short* __restrict__ imatt)
{
    int blk = blockIdx.x, tid = threadIdx.x;
    if (blk < 20800) {
        int i = blk * 256 + tid;
        int c = i % 2080; int bs = i / 2080; int b = bs / NS; int s = bs % NS;
        float v = 0.f;
        if (c < FEAT) {
            v = image[((size_t)b * KOBJ + tidx[b * NS + s]) * FEAT + c];
            timg_f[(size_t)bs * FEAT + c] = v;
        }
        gnodes[(size_t)bs * 3104 + c] = f2bf(v);
    } else if (blk < 20900) {
        int i = (blk - 20800) * 256 + tid;
        if (i >= BATCH * NS * NS) return;
        int m = i % NS; int bn = i / NS; int b = bn / NS; int n = bn % NS;
        const float* bbn = image + ((size_t)b * KOBJ + tidx[b * NS + n]) * FEAT + (FEAT - 4);
        const float* bbm = image + ((size_t)b * KOBJ + tidx[b * NS + m]) * FEAT + (FEAT - 4);
        float cnx = bbn[0] + 0.5f * (bbn[2] - bbn[0]);
        float cny = bbn[1] + 0.5f * (bbn[3] - bbn[1]);
        float cmx = bbm[0] + 0.5f * (bbm[2] - bbm[0]);
        float cmy = bbm[1] + 0.5f * (bbm[3] - bbm[1]);
        float d0 = cnx - cmx, d1 = cny - cmy;
        float rho = sqrtf(d0 * d0 + d1 * d1);
        float theta = atan2f(d0, d1);
        #pragma unroll
        for (int k = 0; k < NK; k++) {
            float a1 = (rho   - mu1[k*2+0]) / (1e-14f + sig1[k*2+0]);
            float b1 = (theta - mu1[k*2+1]) / (1e-14f + sig1[k*2+1]);
            kw1[(size_t)i * NK + k] = expf(-0.5f * (a1*a1 + b1*b1));
            float a2 = (rho   - mu2[k*2+0]) / (1e-14f + sig2[k*2+0]);
            float b2 = (theta - mu2[k*2+1]) / (1e-14f + sig2[k*2+1]);
            kw2[(size_t)i * NK + k] = expf(-0.5f * (a2*a2 + b2*b2));
        }
    } else {
        int i = (blk - 20900) * 256 + tid;
        int c = i % 2080; int b = i / 2080;
        float s = 0.f;
        if (c < FEAT)
            for (int l = 0; l < KOBJ; l++)
                s += image[((size_t)b * KOBJ + l) * FEAT + c] * att[b * KOBJ + l];
        imatt[(size_t)b * 2080 + c] = f2bf(s);
    }
}

// mix1: h1[(b,n),c] = relu(b1[c] + sum_m kw1[b,n,m,c/256]*Y1[(b,m),c]); Y read once
__global__ __launch_bounds__(256)
void mix1_k(const float* __restrict__ Y, const float* __restrict__ kw,
            const float* __restrict__ bias, short* __restrict__ outh)
{
    __shared__ float Yl[NS][256];
    __shared__ float kwl[100];
    int b = blockIdx.x >> 3, ch = blockIdx.x & 7;
    int tid = threadIdx.x;
    int c = ch * 256 + tid;
    #pragma unroll
    for (int m = 0; m < NS; m++)
        Yl[m][tid] = Y[((size_t)b * NS + m) * 2048 + c];
    if (tid < 100) kwl[tid] = kw[((size_t)b * 100 + tid) * NK + ch];
    __syncthreads();
    float bi = bias[c];
    #pragma unroll
    for (int n = 0; n < NS; n++) {
        float s = bi;
        #pragma unroll
        for (int m = 0; m < NS; m++) s += kwl[n * 10 + m] * Yl[m][tid];
        outh[((size_t)b * NS + n) * 2048 + c] = f2bf(fmaxf(s, 0.f));
    }
}

// mix2: KO=128, CT=1024; writes h2_f and gnodes[...,2080+c]
__global__ __launch_bounds__(256)
void mix2_k(const float* __restrict__ Y, const float* __restrict__ kw,
            const float* __restrict__ bias, float* __restrict__ outf,
            short* __restrict__ gnodes)
{
    __shared__ float Yl[NS][256];
    __shared__ float kwl[200];
    int b = blockIdx.x >> 2, ch = blockIdx.x & 3;
    int tid = threadIdx.x;
    int c = ch * 256 + tid;
    #pragma unroll
    for (int m = 0; m < NS; m++)
        Yl[m][tid] = Y[((size_t)b * NS + m) * 1024 + c];
    if (tid < 200) {
        int kk = tid / 100, rr = tid % 100;
        kwl[tid] = kw[((size_t)b * 100 + rr) * NK + ch * 2 + kk];
    }
    __syncthreads();
    int ks = (tid >> 7) * 100;
    float bi = bias[c];
    #pragma unroll
    for (int n = 0; n < NS; n++) {
        float s = bi;
        #pragma unroll
        for (int m = 0; m < NS; m++) s += kwl[ks + n * 10 + m] * Yl[m][tid];
        s = fmaxf(s, 0.f);
        outf[((size_t)b * NS + n) * 1024 + c] = s;
        gnodes[((size_t)b * NS + n) * 3104 + 2080 + c] = f2bf(s);
    }
}

// gatt_cat[b, c] : c<2080 from timg_f(att-weighted), else from h2_f
__global__ void wsumcat_k(const float* __restrict__ timg_f, const float* __restrict__ h2f,
                          const float* __restrict__ att, short* __restrict__ outc)
{
    int i = blockIdx.x * 256 + threadIdx.x;
    int c = i % 3104; int b = i / 3104;
    float s = 0.f;
    if (c < 2080) {
        if (c < FEAT)
            for (int l = 0; l < NS; l++)
                s += timg_f[((size_t)b * NS + l) * FEAT + c] * att[b * NS + l];
    } else {
        int cc = c - 2080;
        for (int l = 0; l < NS; l++)
            s += h2f[((size_t)b * NS + l) * 1024 + cc] * att[b * NS + l];
    }
    outc[(size_t)b * 3104 + c] = f2bf(s);
}

__global__ void add_k(const float* __restrict__ a, const float* __restrict__ b,
                      float* __restrict__ o, int n)
{
    int i = blockIdx.x * 256 + threadIdx.x;
    if (i < n) o[i] = a[i] + b[i];
}

// ==================== host ====================
static GJob mkjob(const short* Ah, const short* Al, const short* Bh, const short* Bl,
                  const float* Bf, long lda, long ldb,
                  float* Cf, short* Cb, long ldc, long ldcb,
                  const float* bias, const float* mul, long ldmul,
                  const float* wmul, float* Cf2, const float* qpw, float* raw, int L,
                  int Nvalid, int K, int beta, int relu)
{
    GJob j; j.Ah=Ah; j.Al=Al; j.Bh=Bh; j.Bl=Bl; j.Bf=Bf; j.lda=lda; j.ldb=ldb;
    j.Cf=Cf; j.Cb=Cb; j.ldc=ldc; j.ldcb=ldcb; j.bias=bias; j.mul=mul; j.ldmul=ldmul;
    j.wmul=wmul; j.Cf2=Cf2; j.qpw=qpw; j.raw=raw; j.L=L; j.Nvalid=Nvalid; j.K=K;
    j.beta=beta; j.relu=relu; return j;
}

extern "C" void kernel_launch(void* const* d_in, const int* in_sizes, int n_in,
                              void* d_out, int out_size, void* d_ws, size_t ws_size,
                              hipStream_t stream)
{
    const int*   question  = (const int*)d_in[0];
    const float* image     = (const float*)d_in[1];
    const int*   qlen      = (const int*)d_in[3];
    const float* wembed    = (const float*)d_in[4];
    const float* gru_wih   = (const float*)d_in[5];
    const float* gru_whh   = (const float*)d_in[6];
    const float* gru_bih   = (const float*)d_in[7];
    const float* gru_bhh   = (const float*)d_in[8];
    const float* ia_img_w  = (const float*)d_in[9];
    const float* ia_img_b  = (const float*)d_in[10];
    const float* ia_txt_w  = (const float*)d_in[11];
    const float* ia_txt_b  = (const float*)d_in[12];
    const float* ia_att_w  = (const float*)d_in[13];
    const float* ga_img_w  = (const float*)d_in[15];
    const float* ga_img_b  = (const float*)d_in[16];
    const float* ga_txt_w  = (const float*)d_in[17];
    const float* ga_txt_b  = (const float*)d_in[18];
    const float* ga_att_w  = (const float*)d_in[19];
    const float* gc1_mu    = (const float*)d_in[21];
    const float* gc1_sigma = (const float*)d_in[22];
    const float* gc1_w     = (const float*)d_in[23];
    const float* gc1_b     = (const float*)d_in[24];
    const float* gc2_mu    = (const float*)d_in[25];
    const float* gc2_sigma = (const float*)d_in[26];
    const float* gc2_w     = (const float*)d_in[27];
    const float* gc2_b     = (const float*)d_in[28];
    const float* out1_w    = (const float*)d_in[29];
    const float* out1_b    = (const float*)d_in[30];
    const float* out2_w    = (const float*)d_in[31];
    const float* out2_b    = (const float*)d_in[32];
    const float* iout1_w   = (const float*)d_in[33];
    const float* iout1_b   = (const float*)d_in[34];
    const float* iout2_w   = (const float*)d_in[35];
    const float* iout2_b   = (const float*)d_in[36];
    float* out = (float*)d_out;

    float* ws = (float*)d_ws;
    size_t off = 0;
    auto alloc  = [&](size_t n)   { size_t o = off; off += (n + 63) & ~(size_t)63; return ws + o; };
    auto allocS = [&](size_t nsh) { return (short*)alloc((nsh + 1) >> 1); };

    // fp32 (att_ia/att_ga contiguous: one zero job covers both)
    float* att_ia = alloc((size_t)BATCH * KOBJ);
    float* att_ga = alloc((size_t)BATCH * NS);
    int*   tidx   = (int*)alloc((size_t)BATCH * NS);
    float* qproj  = alloc(262144);
    float* qpw    = alloc(262144);
    float* qproj2 = alloc(262144);
    float* qpw2   = alloc(262144);
    float* timg_f = alloc((size_t)2560 * FEAT);
    float* kw1    = alloc(204800);
    float* kw2    = alloc(204800);
    float* h0f    = alloc(262144);  short* h0h = allocS(262144);  short* h0l = allocS(262144);
    float* h1f    = alloc(262144);  short* h1h = allocS(262144);  short* h1l = allocS(262144);
    float* h2_f   = alloc(2621440);
    float* gi_all = alloc(11010048);           // reused: Y1, Y2, s1f, s2f
    // bf16
    short* wih_h   = allocS(983040);   short* wih_l   = allocS(983040);
    short* whhp_h  = allocS(3145728);  short* whhp_l  = allocS(3145728);
    short* iaimg_h = allocS(2129920);  short* iaimg_l = allocS(2129920);
    short* iatxt_h = allocS(1048576);  short* iatxt_l = allocS(1048576);
    short* emb_h   = allocS(1146880);  short* emb_l   = allocS(1146880);
    short* gaw_cat = allocS(3178496);          // 1024 x 3104
    short* gatxt_h = allocS(1048576);
    short* gc1t_h  = allocS(4259840);          // 2048 x 2080
    short* gc2t_h  = allocS(2097152);          // 1024 x 2048
    short* gnodes  = allocS(7946240);          // 2560 x 3104
    short* h1_h    = allocS(5242880);          // 2560 x 2048
    short* imatt_h = allocS(532480);           // 256 x 2080
    short* gatt_c  = allocS(794624);           // 256 x 3104
    short* gcomb_h = allocS(262144);
    short* icomb_h = allocS(262144);
    short* hid1_h  = allocS(770048);           // 256 x 3008
    short* hid2_h  = allocS(770048);
    short* img_hh  = allocS(19169280);         // 9216 x 2080
    short* img_ll  = allocS(19169280);

    float* Y1  = gi_all;                       // 2560x2048
    float* Y2  = gi_all + 5242880;             // 2560x1024
    float* s1f = gi_all;                       // 256x3000
    float* s2f = gi_all + 768000;

    // ===== mega conversion (1 launch) =====
    {
        CJobs P{}; int nb = 0, nj = 0;
        auto addc = [&](int type, const float* src, short* dh, short* dl,
                        long sld, int srows, int scols, long dld, int dcols, long nelem) {
            CJob& j = P.j[nj]; j = CJob{};
            j.type = type; j.src = src; j.dh = dh; j.dl = dl;
            j.sld = sld; j.srows = srows; j.scols = scols; j.dld = dld; j.dcols = dcols;
            j.nelem = nelem; j.nblocks = (int)((nelem + 255) / 256); j.b0 = nb;
            nb += j.nblocks; nj++;
        };
        addc(0, gru_wih, wih_h, wih_l, 300, 3072, 300, 320, 320, 983040);
        addc(1, gru_whh, whhp_h, whhp_l, 1024, 3072, 1024, 1024, 1024, 3145728);
        addc(0, ia_img_w, iaimg_h, iaimg_l, FEAT, 1024, FEAT, 2080, 2080, 2129920);
        addc(0, ia_txt_w, iatxt_h, iatxt_l, 1024, 1024, 1024, 1024, 1024, 1048576);
        addc(0, ga_img_w, gaw_cat, nullptr, FEAT + HID, 1024, FEAT, 3104, 2080, 2129920);
        addc(0, ga_img_w + FEAT, gaw_cat + 2080, nullptr, FEAT + HID, 1024, HID, 3104, 1024, 1048576);
        addc(0, ga_txt_w, gatxt_h, nullptr, 1024, 1024, 1024, 1024, 1024, 1048576);
        {   // embed
            CJob& j = P.j[nj]; j = CJob{};
            j.type = 2; j.src = wembed; j.isrc = question; j.dh = emb_h; j.dl = emb_l;
            j.nelem = 1146880; j.nblocks = 4480; j.b0 = nb; nb += 4480; nj++;
        }
        {   // zero h0 trio (contiguous floats: h0f + h0h + h0l)
            CJob& j = P.j[nj]; j = CJob{};
            j.type = 3; j.df = h0f; j.nelem = 262144 + 131072 + 131072;
            j.nblocks = (int)((j.nelem + 255) / 256); j.b0 = nb; nb += j.nblocks; nj++;
        }
        {   // zero att_ia + att_ga (contiguous)
            CJob& j = P.j[nj]; j = CJob{};
            j.type = 3; j.df = att_ia; j.nelem = BATCH * KOBJ + BATCH * NS;
            j.nblocks = (int)((j.nelem + 255) / 256); j.b0 = nb; nb += j.nblocks; nj++;
        }
        {   // packT gc1: 8 slices (2052 x 256) -> (256 x 2080)
            CJob& j = P.j[nj]; j = CJob{};
            j.type = 4; j.src = gc1_w; j.dh = gc1t_h;
            j.srows = FEAT; j.scols = 256; j.dld = 2080; j.dcols = 2080; j.txc = 8;
            j.nblocks = NK * 8 * 65; j.b0 = nb; nb += j.nblocks; nj++;
        }
        {   // packT gc2: 8 slices (2048 x 128) -> (128 x 2048)
            CJob& j = P.j[nj]; j = CJob{};
            j.type = 4; j.src = gc2_w; j.dh = gc2t_h;
            j.srows = 2048; j.scols = 128; j.dld = 2048; j.dcols = 2048; j.txc = 4;
            j.nblocks = NK * 4 * 64; j.b0 = nb; nb += j.nblocks; nj++;
        }
        addc(0, image, img_hh, img_ll, FEAT, 9216, FEAT, 2080, 2080, 19169280);
        P.nj = nj;
        megacvt_k<<<nb, 256, 0, stream>>>(P);
    }

    GJobs G{};
    // ===== Phase A: GRU =====
    G.j[0] = mkjob(emb_h, emb_l, wih_h, wih_l, nullptr, 320, 320,
                   gi_all, nullptr, 3072, 0, gru_bih, nullptr, 0,
                   nullptr, nullptr, nullptr, nullptr, 0, 3072, 320, 0, 0);
    mgemm_k<3,4,0><<<dim3(24, 28, 1), 256, 0, stream>>>(G);
    float* hf[2] = { h0f, h1f }; short* hh[2] = { h0h, h1h }; short* hl[2] = { h0l, h1l };
    for (int t = 0; t < QLEN_; t++) {
        int a = t & 1, b = (t + 1) & 1;
        gru_step_k<<<dim3(8, 8), 256, 0, stream>>>(
            hh[a], hl[a], hf[a], hf[b], hh[b], hl[b],
            whhp_h, whhp_l, gru_bhh, gi_all, qlen, t);
    }
    // final h in buf0 (14 steps, even)

    // ===== qproj (PREC3) -> qproj(relu'd), qpw =====
    G.j[0] = mkjob(h0h, h0l, iatxt_h, iatxt_l, nullptr, 1024, 1024,
                   qproj, nullptr, 1024, 0, ia_txt_b, nullptr, 0,
                   ia_att_w, qpw, nullptr, nullptr, 0, 1024, 1024, 0, 1);
    mgemm_k<3,2,0><<<dim3(8, 4, 1), 256, 0, stream>>>(G);
    // ===== improj ATTRED -> att_ia =====
    G.j[0] = mkjob(img_hh, img_ll, iaimg_h, iaimg_l, nullptr, 2080, 2080,
                   nullptr, nullptr, 0, 0, ia_img_b, nullptr, 0,
                   nullptr, nullptr, qpw, att_ia, KOBJ, 1024, 2080, 0, 1);
    mgemm_k<3,4,0><<<dim3(8, 72, 1), 256, 0, stream>>>(G);
    softmax_topk_k<<<1, 256, 0, stream>>>(att_ia, KOBJ, tidx);
    phasecprep_k<<<22980, 256, 0, stream>>>(image, tidx, att_ia, gnodes, timg_f,
                                            gc1_mu, gc1_sigma, gc2_mu, gc2_sigma,
                                            kw1, kw2, imatt_h);
    // ===== {icomb, qproj2} batched =====
    G.j[0] = mkjob(imatt_h, nullptr, iaimg_h, nullptr, nullptr, 2080, 2080,
                   nullptr, icomb_h, 0, 1024, ia_img_b, qproj, 1024,
                   nullptr, nullptr, nullptr, nullptr, 0, 1024, 2080, 0, 1);
    G.j[1] = mkjob(h0h, nullptr, gatxt_h, nullptr, nullptr, 1024, 1024,
                   qproj2, nullptr, 1024, 0, ga_txt_b, nullptr, 0,
                   ga_att_w, qpw2, nullptr, nullptr, 0, 1024, 1024, 0, 1);
    mgemm_k<1,2,0><<<dim3(8, 4, 2), 256, 0, stream>>>(G);
    // ===== graph convs =====
    G.j[0] = mkjob(gnodes, nullptr, gc1t_h, nullptr, nullptr, 3104, 2080,
                   Y1, nullptr, 2048, 0, nullptr, nullptr, 0,
                   nullptr, nullptr, nullptr, nullptr, 0, 2048, 2080, 0, 0);
    mgemm_k<1,4,0><<<dim3(16, 20, 1), 256, 0, stream>>>(G);
    mix1_k<<<2048, 256, 0, stream>>>(Y1, kw1, gc1_b, h1_h);
    G.j[0] = mkjob(h1_h, nullptr, gc2t_h, nullptr, nullptr, 2048, 2048,
                   Y2, nullptr, 1024, 0, nullptr, nullptr, 0,
                   nullptr, nullptr, nullptr, nullptr, 0, 1024, 2048, 0, 0);
    mgemm_k<1,4,0><<<dim3(8, 20, 1), 256, 0, stream>>>(G);
    mix2_k<<<1024, 256, 0, stream>>>(Y2, kw2, gc2_b, h2_f, gnodes);
    // ===== graph attention: gproj ATTRED -> att_ga =====
    G.j[0] = mkjob(gnodes, nullptr, gaw_cat, nullptr, nullptr, 3104, 3104,
                   nullptr, nullptr, 0, 0, ga_img_b, nullptr, 0,
                   nullptr, nullptr, qpw2, att_ga, NS, 1024, 3104, 0, 1);
    mgemm_k<1,4,0><<<dim3(8, 20, 1), 256, 0, stream>>>(G);
    softmax_topk_k<<<1, 256, 0, stream>>>(att_ga, NS, nullptr);
    wsumcat_k<<<3104, 256, 0, stream>>>(timg_f, h2_f, att_ga, gatt_c);
    G.j[0] = mkjob(gatt_c, nullptr, gaw_cat, nullptr, nullptr, 3104, 3104,
                   nullptr, gcomb_h, 0, 1024, ga_img_b, qproj2, 1024,
                   nullptr, nullptr, nullptr, nullptr, 0, 1024, 3104, 0, 1);
    mgemm_k<1,2,0><<<dim3(8, 4, 1), 256, 0, stream>>>(G);
    // ===== output MLPs (BF32 B-staging) =====
    G.j[0] = mkjob(gcomb_h, nullptr, nullptr, nullptr, out1_w, 1024, 1024,
                   nullptr, hid1_h, 0, 3008, out1_b, nullptr, 0,
                   nullptr, nullptr, nullptr, nullptr, 0, OUTN, 1024, 0, 1);
    G.j[1] = mkjob(icomb_h, nullptr, nullptr, nullptr, iout1_w, 1024, 1024,
                   nullptr, hid2_h, 0, 3008, iout1_b, nullptr, 0,
                   nullptr, nullptr, nullptr, nullptr, 0, OUTN, 1024, 0, 1);
    mgemm_k<1,2,1><<<dim3(24, 4, 2), 256, 0, stream>>>(G);
    G.j[0] = mkjob(hid1_h, nullptr, nullptr, nullptr, out2_w, 3008, OUTN,
                   s1f, nullptr, OUTN, 0, out2_b, nullptr, 0,
                   nullptr, nullptr, nullptr, nullptr, 0, OUTN, 3008, 0, 0);
    G.j[1] = mkjob(hid2_h, nullptr, nullptr, nullptr, iout2_w, 3008, OUTN,
                   s2f, nullptr, OUTN, 0, iout2_b, nullptr, 0,
                   nullptr, nullptr, nullptr, nullptr, 0, OUTN, 3008, 0, 0);
    mgemm_k<1,2,1><<<dim3(24, 4, 2), 256, 0, stream>>>(G);
    add_k<<<3000, 256, 0, stream>>>(s1f, s2f, out, BATCH * OUTN);
}